// Round 13
// baseline (245.126 us; speedup 1.0000x reference)
//
#include <hip/hip_runtime.h>

// GCN 3-layer forward on MI355X.
// CSR build WITHOUT global atomics (memory-side RMW ceiling ~22G/s measured):
//   hist_rank / scan / scatter_part / bucket  (LDS atomics only)
// Compute (segment_sum(M)@W == segment_sum(M@W), matmul before aggregation):
//   mmB:  xb = bf16(ns*(X@W))   LDS-FREE: X rows are wave-uniform -> scalar
//         s_load path (readfirstlane-forced), W coalesced VMEM, pure-FMA VALU
//   agg128 (+fused activation epilogue: relu(nd*acc+b)[*ns]) -> bufA
//   mm40_l3 -> yb (bf16, rows padded 40->64) -> agg40 (8 edges/iter, uint4)

#define EPB 4096          // edges per partition block (256 threads x 16)
#define SCAN_CHUNK 4096

__device__ __forceinline__ ushort f2bf(float f) {
    unsigned u = __float_as_uint(f);
    unsigned r = (u + 0x7fffu + ((u >> 16) & 1u)) >> 16;  // RN-even
    return (ushort)r;
}
__device__ __forceinline__ void unpack2(unsigned w, float& lo, float& hi) {
    lo = __uint_as_float(w << 16);
    hi = __uint_as_float(w & 0xffff0000u);
}

// Pass 1: per-block LDS histograms (dst>>8, src>>8) + in-block ranks.
__global__ __launch_bounds__(256) void hist_rank_kernel(const int* __restrict__ ei, int E,
        int nblk1, int NB, int* __restrict__ hist_all,
        ushort* __restrict__ rankD, ushort* __restrict__ rankS) {
    __shared__ int hd[512];
    __shared__ int hs[512];
    int t = threadIdx.x, blk = blockIdx.x;
    for (int i = t; i < 512; i += 256) { hd[i] = 0; hs[i] = 0; }
    __syncthreads();
    int base = blk * EPB;
    #pragma unroll
    for (int j = 0; j < 16; ++j) {
        int e = base + j * 256 + t;
        if (e < E) {
            int s = ei[e], d = ei[E + e];
            rankS[e] = (ushort)atomicAdd(&hs[s >> 8], 1);
            rankD[e] = (ushort)atomicAdd(&hd[d >> 8], 1);
        }
    }
    __syncthreads();
    int L = NB * nblk1;
    for (int b = t; b < NB; b += 256) {
        hist_all[b * nblk1 + blk]     = hd[b];
        hist_all[L + b * nblk1 + blk] = hs[b];
    }
}

// Generic hierarchical exclusive scan over data[0..L2)
__global__ __launch_bounds__(256) void scanA_kernel(const int* __restrict__ data, int L2,
                                                    int* __restrict__ partials) {
    __shared__ int red[256];
    int t = threadIdx.x;
    int base = blockIdx.x * SCAN_CHUNK;
    int s = 0;
    for (int i = t; i < SCAN_CHUNK; i += 256) {
        int idx = base + i;
        if (idx < L2) s += data[idx];
    }
    red[t] = s;
    __syncthreads();
    for (int off = 128; off > 0; off >>= 1) {
        if (t < off) red[t] += red[t + off];
        __syncthreads();
    }
    if (t == 0) partials[blockIdx.x] = red[0];
}

__global__ __launch_bounds__(256) void scanB_kernel(int* __restrict__ partials, int nparts) {
    __shared__ int s[256];
    int t = threadIdx.x;
    s[t] = (t < nparts) ? partials[t] : 0;
    __syncthreads();
    for (int off = 1; off < 256; off <<= 1) {
        int v = (t >= off) ? s[t - off] : 0;
        __syncthreads();
        s[t] += v;
        __syncthreads();
    }
    if (t < nparts) partials[t] = s[t] - partials[t];
}

__global__ __launch_bounds__(256) void scanC_kernel(int* __restrict__ data, int L2,
                                                    const int* __restrict__ partials) {
    __shared__ int tsum[256];
    int t = threadIdx.x;
    int base = blockIdx.x * SCAN_CHUNK + t * 16;
    int local[16];
    int s = 0;
    #pragma unroll
    for (int i = 0; i < 16; ++i) {
        int idx = base + i;
        int v = (idx < L2) ? data[idx] : 0;
        local[i] = v;
        s += v;
    }
    tsum[t] = s;
    __syncthreads();
    for (int off = 1; off < 256; off <<= 1) {
        int v = (t >= off) ? tsum[t - off] : 0;
        __syncthreads();
        tsum[t] += v;
        __syncthreads();
    }
    int run = partials[blockIdx.x] + (t ? tsum[t - 1] : 0);
    #pragma unroll
    for (int i = 0; i < 16; ++i) {
        int idx = base + i;
        if (idx < L2) {
            data[idx] = run;
            run += local[i];
        }
    }
}

// Pass 1c: scatter into bucket partitions using scanned bases + stored ranks.
__global__ __launch_bounds__(256) void scatter_part_kernel(const int* __restrict__ ei, int E,
        int nblk1, int NB, const int* __restrict__ hist_all,
        const ushort* __restrict__ rankD, const ushort* __restrict__ rankS,
        unsigned* __restrict__ packD, unsigned char* __restrict__ srcb) {
    int t = threadIdx.x, blk = blockIdx.x;
    int base = blk * EPB;
    int L = NB * nblk1;
    #pragma unroll
    for (int j = 0; j < 16; ++j) {
        int e = base + j * 256 + t;
        if (e < E) {
            int s = ei[e], d = ei[E + e];
            int posD = hist_all[(d >> 8) * nblk1 + blk] + (int)rankD[e];
            packD[posD] = ((unsigned)(d & 255) << 24) | (unsigned)s;
            int posS = hist_all[L + (s >> 8) * nblk1 + blk] - E + (int)rankS[e];
            srcb[posS] = (unsigned char)(s & 255);
        }
    }
}

// Pass 2: blocks [0,NB): dst-bucket -> row_ptr, norm_dst, ranked col placement.
//         blocks [NB,2NB): src-bucket -> norm_src. LDS atomics only.
__global__ __launch_bounds__(256) void bucket_kernel(const unsigned* __restrict__ packD,
        const unsigned char* __restrict__ srcb, const int* __restrict__ hist_all,
        int nblk1, int NB, int n, int E,
        int* __restrict__ row_ptr, int* __restrict__ col,
        float* __restrict__ norm_src, float* __restrict__ norm_dst) {
    int t = threadIdx.x;
    __shared__ int cnt[256];
    __shared__ int incl[256];
    __shared__ int cur[256];
    if ((int)blockIdx.x < NB) {
        int B = blockIdx.x;
        int s0 = hist_all[B * nblk1];
        int s1 = (B + 1 < NB) ? hist_all[(B + 1) * nblk1] : E;
        cnt[t] = 0;
        __syncthreads();
        for (int i = s0 + t; i < s1; i += 256)
            atomicAdd(&cnt[packD[i] >> 24], 1);
        __syncthreads();
        int v = cnt[t];
        incl[t] = v;
        __syncthreads();
        for (int off = 1; off < 256; off <<= 1) {
            int w = (t >= off) ? incl[t - off] : 0;
            __syncthreads();
            incl[t] += w;
            __syncthreads();
        }
        int excl = incl[t] - v;
        cur[t] = excl;
        int node = B * 256 + t;
        if (node < n) {
            row_ptr[node] = s0 + excl;
            norm_dst[node] = rsqrtf((float)(v > 0 ? v : 1));
        }
        if (B == NB - 1 && t == 0) row_ptr[n] = E;
        __syncthreads();
        for (int i = s0 + t; i < s1; i += 256) {
            unsigned p = packD[i];
            int r = atomicAdd(&cur[p >> 24], 1);
            col[s0 + r] = (int)(p & 0xFFFFFFu);
        }
    } else {
        int B = (int)blockIdx.x - NB;
        int L = NB * nblk1;
        int s0 = hist_all[L + B * nblk1] - E;
        int s1 = (B + 1 < NB) ? (hist_all[L + (B + 1) * nblk1] - E) : E;
        cnt[t] = 0;
        __syncthreads();
        for (int i = s0 + t; i < s1; i += 256)
            atomicAdd(&cnt[srcb[i]], 1);
        __syncthreads();
        int node = B * 256 + t;
        if (node < n) {
            int v = cnt[t];
            norm_src[node] = rsqrtf((float)(v > 0 ? v : 1));
        }
    }
}

// mmB: out[r][c] = bf16( ns[r] * (X[r][:] @ W[:,c]) ), W 128x128 row-major.
// LDS-free: wave w -> rows (blockIdx*4+w)*8 .. +7, lane -> cols (lane, lane+64).
// X row pointers are wave-uniform (readfirstlane) -> scalar s_load path;
// W loads coalesced VMEM; VALU does (almost) pure FMA.
__global__ __launch_bounds__(256, 8) void mmB_kernel(const float* __restrict__ X,
        const float* __restrict__ W, const float* __restrict__ ns,
        ushort* __restrict__ out, int n) {
    int t = threadIdx.x;
    int wv = __builtin_amdgcn_readfirstlane(t >> 6);
    int lane = t & 63;
    int row0 = ((int)blockIdx.x * 4 + wv) * 8;
    if (row0 >= n) return;
    int c0 = lane, c1 = lane + 64;
    float acc0[8], acc1[8];
    #pragma unroll
    for (int r = 0; r < 8; ++r) { acc0[r] = 0.f; acc1[r] = 0.f; }
    // Clamp row base so loads stay in-bounds on the tail block; stores guarded.
    int rlim = (row0 + 8 <= n) ? 8 : (n - row0);
    const float* xp = X + (size_t)row0 * 128;
    const float* Wp0 = W + c0;
    const float* Wp1 = W + c1;
    if (rlim == 8) {
        for (int k = 0; k < 128; k += 4) {
            float w00 = Wp0[(k + 0) * 128], w10 = Wp1[(k + 0) * 128];
            float w01 = Wp0[(k + 1) * 128], w11 = Wp1[(k + 1) * 128];
            float w02 = Wp0[(k + 2) * 128], w12 = Wp1[(k + 2) * 128];
            float w03 = Wp0[(k + 3) * 128], w13 = Wp1[(k + 3) * 128];
            #pragma unroll
            for (int r = 0; r < 8; ++r) {
                float4 xv = *reinterpret_cast<const float4*>(xp + r * 128 + k);
                acc0[r] = fmaf(xv.x, w00, acc0[r]);
                acc1[r] = fmaf(xv.x, w10, acc1[r]);
                acc0[r] = fmaf(xv.y, w01, acc0[r]);
                acc1[r] = fmaf(xv.y, w11, acc1[r]);
                acc0[r] = fmaf(xv.z, w02, acc0[r]);
                acc1[r] = fmaf(xv.z, w12, acc1[r]);
                acc0[r] = fmaf(xv.w, w03, acc0[r]);
                acc1[r] = fmaf(xv.w, w13, acc1[r]);
            }
        }
    } else {
        for (int k = 0; k < 128; k += 4) {
            float w00 = Wp0[(k + 0) * 128], w10 = Wp1[(k + 0) * 128];
            float w01 = Wp0[(k + 1) * 128], w11 = Wp1[(k + 1) * 128];
            float w02 = Wp0[(k + 2) * 128], w12 = Wp1[(k + 2) * 128];
            float w03 = Wp0[(k + 3) * 128], w13 = Wp1[(k + 3) * 128];
            for (int r = 0; r < rlim; ++r) {
                float4 xv = *reinterpret_cast<const float4*>(xp + r * 128 + k);
                acc0[r] = fmaf(xv.x, w00, acc0[r]);
                acc1[r] = fmaf(xv.x, w10, acc1[r]);
                acc0[r] = fmaf(xv.y, w01, acc0[r]);
                acc1[r] = fmaf(xv.y, w11, acc1[r]);
                acc0[r] = fmaf(xv.z, w02, acc0[r]);
                acc1[r] = fmaf(xv.z, w12, acc1[r]);
                acc0[r] = fmaf(xv.w, w03, acc0[r]);
                acc1[r] = fmaf(xv.w, w13, acc1[r]);
            }
        }
    }
    #pragma unroll
    for (int r = 0; r < 8; ++r) {
        int gr = row0 + r;
        if (r < rlim) {
            float s = ns[gr];
            out[(size_t)gr * 128 + c0] = f2bf(s * acc0[r]);
            out[(size_t)gr * 128 + c1] = f2bf(s * acc1[r]);
        }
    }
}

// One wave per node: acc = sum_{u->v} xb[u][:] (bf16 rows, fp32 accum), then
// fused activation epilogue: out = relu(nd*acc + bias) * (mode ? ns : 1).
__global__ __launch_bounds__(256) void agg128_kernel(const ushort* __restrict__ xb,
        const int* __restrict__ row_ptr, const int* __restrict__ col,
        const float* __restrict__ bias, const float* __restrict__ norm_dst,
        const float* __restrict__ norm_src, float* __restrict__ out, int n, int mode) {
    int wid  = (blockIdx.x * blockDim.x + threadIdx.x) >> 6;
    int lane = threadIdx.x & 63;
    if (wid >= n) return;
    int start = row_ptr[wid], end = row_ptr[wid + 1];
    int quarter = lane >> 4, l4 = lane & 15;
    float acc[8];
    #pragma unroll
    for (int i = 0; i < 8; ++i) acc[i] = 0.f;
    for (int b = start; b < end; b += 64) {
        int m = end - b; if (m > 64) m = 64;
        int u = 0;
        if (lane < m) u = col[b + lane];
        for (int j = 0; j < m; j += 4) {
            int jj = j + quarter;
            int uu = __shfl(u, jj);
            if (jj < m) {
                const uint4 v = *reinterpret_cast<const uint4*>(xb + (size_t)uu * 128 + 8 * l4);
                float f0, f1;
                unpack2(v.x, f0, f1); acc[0] += f0; acc[1] += f1;
                unpack2(v.y, f0, f1); acc[2] += f0; acc[3] += f1;
                unpack2(v.z, f0, f1); acc[4] += f0; acc[5] += f1;
                unpack2(v.w, f0, f1); acc[6] += f0; acc[7] += f1;
            }
        }
    }
    #pragma unroll
    for (int i = 0; i < 8; ++i) {
        acc[i] += __shfl_xor(acc[i], 16);
        acc[i] += __shfl_xor(acc[i], 32);
    }
    if (lane < 16) {
        float nd = norm_dst[wid];
        float sc = mode ? norm_src[wid] : 1.f;
        const float* bp = bias + 8 * lane;
        float o[8];
        #pragma unroll
        for (int i = 0; i < 8; ++i)
            o[i] = fmaxf(fmaf(nd, acc[i], bp[i]), 0.f) * sc;
        float* op = out + (size_t)wid * 128 + 8 * lane;
        *reinterpret_cast<float4*>(op)     = make_float4(o[0], o[1], o[2], o[3]);
        *reinterpret_cast<float4*>(op + 4) = make_float4(o[4], o[5], o[6], o[7]);
    }
}

// Layer 3 mm: yb = bf16(X@W3), rows padded 40->64 bf16 (zeros). LDS-free,
// wave -> 8 rows, lane -> col (clamped >=40). X rows wave-uniform (s_load).
__global__ __launch_bounds__(256, 8) void mm40_kernel(const float* __restrict__ X,
        const float* __restrict__ W3, ushort* __restrict__ yb, int n) {
    int t = threadIdx.x;
    int wv = __builtin_amdgcn_readfirstlane(t >> 6);
    int lane = t & 63;
    int row0 = ((int)blockIdx.x * 4 + wv) * 8;
    if (row0 >= n) return;
    int c = (lane < 40) ? lane : 0;
    float acc[8];
    #pragma unroll
    for (int r = 0; r < 8; ++r) acc[r] = 0.f;
    int rlim = (row0 + 8 <= n) ? 8 : (n - row0);
    const float* xp = X + (size_t)row0 * 128;
    const float* Wp = W3 + c;
    if (rlim == 8) {
        for (int k = 0; k < 128; k += 4) {
            float w0 = Wp[(k + 0) * 40];
            float w1 = Wp[(k + 1) * 40];
            float w2 = Wp[(k + 2) * 40];
            float w3 = Wp[(k + 3) * 40];
            #pragma unroll
            for (int r = 0; r < 8; ++r) {
                float4 xv = *reinterpret_cast<const float4*>(xp + r * 128 + k);
                acc[r] = fmaf(xv.x, w0, acc[r]);
                acc[r] = fmaf(xv.y, w1, acc[r]);
                acc[r] = fmaf(xv.z, w2, acc[r]);
                acc[r] = fmaf(xv.w, w3, acc[r]);
            }
        }
    } else {
        for (int k = 0; k < 128; k += 4) {
            float w0 = Wp[(k + 0) * 40];
            float w1 = Wp[(k + 1) * 40];
            float w2 = Wp[(k + 2) * 40];
            float w3 = Wp[(k + 3) * 40];
            for (int r = 0; r < rlim; ++r) {
                float4 xv = *reinterpret_cast<const float4*>(xp + r * 128 + k);
                acc[r] = fmaf(xv.x, w0, acc[r]);
                acc[r] = fmaf(xv.y, w1, acc[r]);
                acc[r] = fmaf(xv.z, w2, acc[r]);
                acc[r] = fmaf(xv.w, w3, acc[r]);
            }
        }
    }
    #pragma unroll
    for (int r = 0; r < 8; ++r) {
        int gr = row0 + r;
        if (r < rlim)
            yb[(size_t)gr * 64 + lane] = (lane < 40) ? f2bf(acc[r]) : (ushort)0;
    }
}

// out[v][c] = norm_dst[v] * sum_{u->v} yb[u][c] + b3[c], c < 40.
// One wave/node, 8 edges/iter: octant=lane>>3 picks edge, l8=lane&7 loads
// uint4 (8 bf16 dims). Octant shfl_xor reduce; lanes l8<5 write 8 floats.
__global__ __launch_bounds__(256) void agg40_kernel(const ushort* __restrict__ yb,
        const int* __restrict__ row_ptr, const int* __restrict__ col,
        const float* __restrict__ norm_dst, const float* __restrict__ b3,
        float* __restrict__ out, int n) {
    int wid  = (blockIdx.x * blockDim.x + threadIdx.x) >> 6;
    int lane = threadIdx.x & 63;
    if (wid >= n) return;
    int start = row_ptr[wid], end = row_ptr[wid + 1];
    int oct = lane >> 3, l8 = lane & 7;
    float acc[8];
    #pragma unroll
    for (int i = 0; i < 8; ++i) acc[i] = 0.f;
    for (int b = start; b < end; b += 64) {
        int m = end - b; if (m > 64) m = 64;
        int u = 0;
        if (lane < m) u = col[b + lane];
        for (int j = 0; j < m; j += 8) {
            int jj = j + oct;
            int uu = __shfl(u, jj);
            if (jj < m) {
                const uint4 v = *reinterpret_cast<const uint4*>(yb + (size_t)uu * 64 + 8 * l8);
                float f0, f1;
                unpack2(v.x, f0, f1); acc[0] += f0; acc[1] += f1;
                unpack2(v.y, f0, f1); acc[2] += f0; acc[3] += f1;
                unpack2(v.z, f0, f1); acc[4] += f0; acc[5] += f1;
                unpack2(v.w, f0, f1); acc[6] += f0; acc[7] += f1;
            }
        }
    }
    #pragma unroll
    for (int i = 0; i < 8; ++i) {
        acc[i] += __shfl_xor(acc[i], 8);
        acc[i] += __shfl_xor(acc[i], 16);
        acc[i] += __shfl_xor(acc[i], 32);
    }
    if (lane < 5) {  // oct==0, l8 0..4 -> dims l8*8 .. l8*8+7 (40 total)
        float nd = norm_dst[wid];
        const float* bp = b3 + 8 * lane;
        float* op = out + (size_t)wid * 40 + 8 * lane;
        float4 o0, o1;
        o0.x = fmaf(nd, acc[0], bp[0]); o0.y = fmaf(nd, acc[1], bp[1]);
        o0.z = fmaf(nd, acc[2], bp[2]); o0.w = fmaf(nd, acc[3], bp[3]);
        o1.x = fmaf(nd, acc[4], bp[4]); o1.y = fmaf(nd, acc[5], bp[5]);
        o1.z = fmaf(nd, acc[6], bp[6]); o1.w = fmaf(nd, acc[7], bp[7]);
        *reinterpret_cast<float4*>(op)     = o0;
        *reinterpret_cast<float4*>(op + 4) = o1;
    }
}

extern "C" void kernel_launch(void* const* d_in, const int* in_sizes, int n_in,
                              void* d_out, int out_size, void* d_ws, size_t ws_size,
                              hipStream_t stream) {
    const float* features = (const float*)d_in[0];
    const int*   ei       = (const int*)d_in[1];
    const float* W1 = (const float*)d_in[2];
    const float* b1 = (const float*)d_in[3];
    const float* W2 = (const float*)d_in[4];
    const float* b2 = (const float*)d_in[5];
    const float* W3 = (const float*)d_in[6];
    const float* b3 = (const float*)d_in[7];

    const int n = in_sizes[0] / 128;
    const int E = in_sizes[1] / 2;

    const int nblk1 = (E + EPB - 1) / EPB;      // partition blocks (196)
    const int NB    = (n + 255) >> 8;           // buckets (196)
    const int L     = NB * nblk1;
    const int L2    = 2 * L;                    // D hist + S hist
    const int sb2   = (L2 + SCAN_CHUNK - 1) / SCAN_CHUNK;

    char* w = (char*)d_ws;
    auto alloc = [&](size_t bytes) {
        char* p = w;
        w += (bytes + 255) & ~(size_t)255;
        return p;
    };
    int*    hist_all = (int*)   alloc((size_t)L2 * 4);
    int*    partials = (int*)   alloc((size_t)256 * 4);
    float*  norm_src = (float*) alloc((size_t)n * 4);
    float*  norm_dst = (float*) alloc((size_t)n * 4);
    int*    row_ptr  = (int*)   alloc((size_t)(n + 1) * 4);
    int*    col      = (int*)   alloc((size_t)E * 4);
    ushort* xb       = (ushort*)alloc((size_t)n * 128 * 2);  // bf16 table; yb aliases
    float*  bufA     = (float*) alloc((size_t)n * 128 * 4);  // activated agg; CSR scratch aliases

    // CSR-build scratch aliases bufA (consumed by bucket_kernel before agg128 writes bufA).
    char* scr = (char*)bufA;
    ushort*        rankD = (ushort*)scr;                 scr += ((size_t)E * 2 + 255) & ~(size_t)255;
    ushort*        rankS = (ushort*)scr;                 scr += ((size_t)E * 2 + 255) & ~(size_t)255;
    unsigned*      packD = (unsigned*)scr;               scr += ((size_t)E * 4 + 255) & ~(size_t)255;
    unsigned char* srcb  = (unsigned char*)scr;
    ushort* yb = xb;   // yb (n*64 bf16) aliases xb; xb2 consumed by agg128 #2
                       // before mm40 writes yb

    int mmb = (n + 31) / 32;   // 4 waves x 8 rows per block
    int ab  = (n + 3) / 4;

    hist_rank_kernel<<<nblk1, 256, 0, stream>>>(ei, E, nblk1, NB, hist_all, rankD, rankS);
    scanA_kernel<<<sb2, 256, 0, stream>>>(hist_all, L2, partials);
    scanB_kernel<<<1, 256, 0, stream>>>(partials, sb2);
    scanC_kernel<<<sb2, 256, 0, stream>>>(hist_all, L2, partials);
    scatter_part_kernel<<<nblk1, 256, 0, stream>>>(ei, E, nblk1, NB, hist_all,
                                                   rankD, rankS, packD, srcb);
    bucket_kernel<<<2 * NB, 256, 0, stream>>>(packD, srcb, hist_all, nblk1, NB, n, E,
                                              row_ptr, col, norm_src, norm_dst);
    mmB_kernel<<<mmb, 256, 0, stream>>>(features, W1, norm_src, xb, n);
    agg128_kernel<<<ab, 256, 0, stream>>>(xb, row_ptr, col, b1, norm_dst, norm_src,
                                          bufA, n, 0);
    mmB_kernel<<<mmb, 256, 0, stream>>>(bufA, W2, norm_src, xb, n);
    agg128_kernel<<<ab, 256, 0, stream>>>(xb, row_ptr, col, b2, norm_dst, norm_src,
                                          bufA, n, 1);
    mm40_kernel<<<mmb, 256, 0, stream>>>(bufA, W3, yb, n);
    agg40_kernel<<<ab, 256, 0, stream>>>(yb, row_ptr, col, norm_dst, b3, (float*)d_out, n);
}

// Round 14
// 193.147 us; speedup vs baseline: 1.2691x; 1.2691x over previous
//
#include <hip/hip_runtime.h>

// GCN 3-layer forward on MI355X.
// CSR build WITHOUT global atomics (memory-side RMW ceiling ~22G/s measured):
//   hist_rank / scan / scatter_part / bucket  (LDS atomics only)
// Compute (segment_sum(M)@W == segment_sum(M@W), matmul before aggregation),
// ALL matmuls on matrix cores (mfma_f32_16x16x32_bf16), bf16 node tables:
//   cvt: fb = bf16(features); prep: W1,W2,W3 -> bf16 frag-swizzled
//   mm1: xb = bf16(ns*(fb@W1))          [MFMA, wave=16 rows x 128 cols]
//   agg128 -> hb = bf16(relu(nd*acc+b1))
//   mm2: xb = bf16(ns*(hb@W2))
//   agg128 -> hb = bf16(relu(nd*acc+b2)*ns)
//   mm3: yb = bf16(hb@W3) padded 40->64
//   agg40 -> out (fp32)

#define EPB 4096
#define SCAN_CHUNK 4096

typedef short v8s __attribute__((ext_vector_type(8)));
typedef float v4f __attribute__((ext_vector_type(4)));

__device__ __forceinline__ ushort f2bf(float f) {
    unsigned u = __float_as_uint(f);
    unsigned r = (u + 0x7fffu + ((u >> 16) & 1u)) >> 16;  // RN-even
    return (ushort)r;
}
__device__ __forceinline__ void unpack2(unsigned w, float& lo, float& hi) {
    lo = __uint_as_float(w << 16);
    hi = __uint_as_float(w & 0xffff0000u);
}

// ---------------- CSR build (unchanged) ----------------
__global__ __launch_bounds__(256) void hist_rank_kernel(const int* __restrict__ ei, int E,
        int nblk1, int NB, int* __restrict__ hist_all,
        ushort* __restrict__ rankD, ushort* __restrict__ rankS) {
    __shared__ int hd[512];
    __shared__ int hs[512];
    int t = threadIdx.x, blk = blockIdx.x;
    for (int i = t; i < 512; i += 256) { hd[i] = 0; hs[i] = 0; }
    __syncthreads();
    int base = blk * EPB;
    #pragma unroll
    for (int j = 0; j < 16; ++j) {
        int e = base + j * 256 + t;
        if (e < E) {
            int s = ei[e], d = ei[E + e];
            rankS[e] = (ushort)atomicAdd(&hs[s >> 8], 1);
            rankD[e] = (ushort)atomicAdd(&hd[d >> 8], 1);
        }
    }
    __syncthreads();
    int L = NB * nblk1;
    for (int b = t; b < NB; b += 256) {
        hist_all[b * nblk1 + blk]     = hd[b];
        hist_all[L + b * nblk1 + blk] = hs[b];
    }
}

__global__ __launch_bounds__(256) void scanA_kernel(const int* __restrict__ data, int L2,
                                                    int* __restrict__ partials) {
    __shared__ int red[256];
    int t = threadIdx.x;
    int base = blockIdx.x * SCAN_CHUNK;
    int s = 0;
    for (int i = t; i < SCAN_CHUNK; i += 256) {
        int idx = base + i;
        if (idx < L2) s += data[idx];
    }
    red[t] = s;
    __syncthreads();
    for (int off = 128; off > 0; off >>= 1) {
        if (t < off) red[t] += red[t + off];
        __syncthreads();
    }
    if (t == 0) partials[blockIdx.x] = red[0];
}

__global__ __launch_bounds__(256) void scanB_kernel(int* __restrict__ partials, int nparts) {
    __shared__ int s[256];
    int t = threadIdx.x;
    s[t] = (t < nparts) ? partials[t] : 0;
    __syncthreads();
    for (int off = 1; off < 256; off <<= 1) {
        int v = (t >= off) ? s[t - off] : 0;
        __syncthreads();
        s[t] += v;
        __syncthreads();
    }
    if (t < nparts) partials[t] = s[t] - partials[t];
}

__global__ __launch_bounds__(256) void scanC_kernel(int* __restrict__ data, int L2,
                                                    const int* __restrict__ partials) {
    __shared__ int tsum[256];
    int t = threadIdx.x;
    int base = blockIdx.x * SCAN_CHUNK + t * 16;
    int local[16];
    int s = 0;
    #pragma unroll
    for (int i = 0; i < 16; ++i) {
        int idx = base + i;
        int v = (idx < L2) ? data[idx] : 0;
        local[i] = v;
        s += v;
    }
    tsum[t] = s;
    __syncthreads();
    for (int off = 1; off < 256; off <<= 1) {
        int v = (t >= off) ? tsum[t - off] : 0;
        __syncthreads();
        tsum[t] += v;
        __syncthreads();
    }
    int run = partials[blockIdx.x] + (t ? tsum[t - 1] : 0);
    #pragma unroll
    for (int i = 0; i < 16; ++i) {
        int idx = base + i;
        if (idx < L2) {
            data[idx] = run;
            run += local[i];
        }
    }
}

__global__ __launch_bounds__(256) void scatter_part_kernel(const int* __restrict__ ei, int E,
        int nblk1, int NB, const int* __restrict__ hist_all,
        const ushort* __restrict__ rankD, const ushort* __restrict__ rankS,
        unsigned* __restrict__ packD, unsigned char* __restrict__ srcb) {
    int t = threadIdx.x, blk = blockIdx.x;
    int base = blk * EPB;
    int L = NB * nblk1;
    #pragma unroll
    for (int j = 0; j < 16; ++j) {
        int e = base + j * 256 + t;
        if (e < E) {
            int s = ei[e], d = ei[E + e];
            int posD = hist_all[(d >> 8) * nblk1 + blk] + (int)rankD[e];
            packD[posD] = ((unsigned)(d & 255) << 24) | (unsigned)s;
            int posS = hist_all[L + (s >> 8) * nblk1 + blk] - E + (int)rankS[e];
            srcb[posS] = (unsigned char)(s & 255);
        }
    }
}

__global__ __launch_bounds__(256) void bucket_kernel(const unsigned* __restrict__ packD,
        const unsigned char* __restrict__ srcb, const int* __restrict__ hist_all,
        int nblk1, int NB, int n, int E,
        int* __restrict__ row_ptr, int* __restrict__ col,
        float* __restrict__ norm_src, float* __restrict__ norm_dst) {
    int t = threadIdx.x;
    __shared__ int cnt[256];
    __shared__ int incl[256];
    __shared__ int cur[256];
    if ((int)blockIdx.x < NB) {
        int B = blockIdx.x;
        int s0 = hist_all[B * nblk1];
        int s1 = (B + 1 < NB) ? hist_all[(B + 1) * nblk1] : E;
        cnt[t] = 0;
        __syncthreads();
        for (int i = s0 + t; i < s1; i += 256)
            atomicAdd(&cnt[packD[i] >> 24], 1);
        __syncthreads();
        int v = cnt[t];
        incl[t] = v;
        __syncthreads();
        for (int off = 1; off < 256; off <<= 1) {
            int w = (t >= off) ? incl[t - off] : 0;
            __syncthreads();
            incl[t] += w;
            __syncthreads();
        }
        int excl = incl[t] - v;
        cur[t] = excl;
        int node = B * 256 + t;
        if (node < n) {
            row_ptr[node] = s0 + excl;
            norm_dst[node] = rsqrtf((float)(v > 0 ? v : 1));
        }
        if (B == NB - 1 && t == 0) row_ptr[n] = E;
        __syncthreads();
        for (int i = s0 + t; i < s1; i += 256) {
            unsigned p = packD[i];
            int r = atomicAdd(&cur[p >> 24], 1);
            col[s0 + r] = (int)(p & 0xFFFFFFu);
        }
    } else {
        int B = (int)blockIdx.x - NB;
        int L = NB * nblk1;
        int s0 = hist_all[L + B * nblk1] - E;
        int s1 = (B + 1 < NB) ? (hist_all[L + (B + 1) * nblk1] - E) : E;
        cnt[t] = 0;
        __syncthreads();
        for (int i = s0 + t; i < s1; i += 256)
            atomicAdd(&cnt[srcb[i]], 1);
        __syncthreads();
        int node = B * 256 + t;
        if (node < n) {
            int v = cnt[t];
            norm_src[node] = rsqrtf((float)(v > 0 ? v : 1));
        }
    }
}

// ---------------- bf16 prep ----------------
// fb = bf16(features)
__global__ __launch_bounds__(256) void cvt_kernel(const float* __restrict__ x,
        ushort* __restrict__ fb, int total4) {
    int i = blockIdx.x * 256 + threadIdx.x;
    if (i >= total4) return;
    float4 v = reinterpret_cast<const float4*>(x)[i];
    ushort4 o;
    o.x = f2bf(v.x); o.y = f2bf(v.y); o.z = f2bf(v.z); o.w = f2bf(v.w);
    reinterpret_cast<ushort4*>(fb)[i] = o;
}

// Swizzle W (row-major [K][Dout] fp32) into MFMA B-frag layout, bf16:
// entry base=(ks*NF+f)*64+lane holds 8 bf16: W[ks*32+(lane>>4)*8+j][f*16+(lane&15)]
__global__ __launch_bounds__(256) void prep_w_kernel(const float* __restrict__ W1,
        const float* __restrict__ W2, const float* __restrict__ W3,
        ushort* __restrict__ W1f, ushort* __restrict__ W2f, ushort* __restrict__ W3f) {
    int idx = blockIdx.x * 256 + threadIdx.x;
    const float* W; ushort* Wf; int Dout, NF, base;
    if (idx < 2048)      { W = W1; Wf = W1f; Dout = 128; NF = 8; base = idx; }
    else if (idx < 4096) { W = W2; Wf = W2f; Dout = 128; NF = 8; base = idx - 2048; }
    else if (idx < 5120) { W = W3; Wf = W3f; Dout = 40;  NF = 4; base = idx - 4096; }
    else return;
    int lane = base & 63;
    int f = (base >> 6) % NF;
    int ks = base / (64 * NF);
    int c = f * 16 + (lane & 15);
    int kbase = ks * 32 + (lane >> 4) * 8;
    unsigned p[4];
    #pragma unroll
    for (int j = 0; j < 4; ++j) {
        float wlo = (c < Dout) ? W[(size_t)(kbase + 2 * j) * Dout + c] : 0.f;
        float whi = (c < Dout) ? W[(size_t)(kbase + 2 * j + 1) * Dout + c] : 0.f;
        p[j] = (unsigned)f2bf(wlo) | ((unsigned)f2bf(whi) << 16);
    }
    *reinterpret_cast<uint4*>(Wf + (size_t)base * 8) = make_uint4(p[0], p[1], p[2], p[3]);
}

// ---------------- MFMA matmul ----------------
// Wave computes 16 rows x NF*16 cols of X@W. A: X[row=lane&15][k=(lane>>4)*8+j]
// (16B/lane, wave covers 16 rows x 64B = fully coalesced). B from pre-swizzled Wf.
// C/D: col=lane&15, row=(lane>>4)*4+reg (m89-verified). Epilogue: bf16(ns? * acc).
template<int NF, int DO_NS>
__global__ __launch_bounds__(256) void mm_mfma_kernel(const ushort* __restrict__ X,
        const ushort* __restrict__ Wf, const float* __restrict__ ns,
        ushort* __restrict__ out, int n) {
    int t = threadIdx.x;
    int wv = t >> 6, lane = t & 63;
    int row0 = ((int)blockIdx.x * 4 + wv) * 16;
    if (row0 >= n) return;
    int arow = row0 + (lane & 15);
    if (arow >= n) arow = n - 1;  // clamp loads; stores guarded
    int kgrp = lane >> 4;
    const v8s* ap = reinterpret_cast<const v8s*>(X + (size_t)arow * 128);
    const v8s* bp = reinterpret_cast<const v8s*>(Wf);
    v4f acc[NF];
    #pragma unroll
    for (int f = 0; f < NF; ++f) acc[f] = (v4f){0.f, 0.f, 0.f, 0.f};
    #pragma unroll
    for (int ks = 0; ks < 4; ++ks) {
        v8s a = ap[ks * 4 + kgrp];
        #pragma unroll
        for (int f = 0; f < NF; ++f) {
            v8s b = bp[(ks * NF + f) * 64 + lane];
            acc[f] = __builtin_amdgcn_mfma_f32_16x16x32_bf16(a, b, acc[f], 0, 0, 0);
        }
    }
    int rbase = row0 + (lane >> 4) * 4;
    int ccol = lane & 15;
    constexpr int OS = NF * 16;
    #pragma unroll
    for (int r = 0; r < 4; ++r) {
        int gr = rbase + r;
        if (gr < n) {
            float s = DO_NS ? ns[gr] : 1.f;
            #pragma unroll
            for (int f = 0; f < NF; ++f)
                out[(size_t)gr * OS + f * 16 + ccol] = f2bf(s * acc[f][r]);
        }
    }
}

// ---------------- aggregation ----------------
// One wave/node: acc = sum_{u->v} xb[u][:] (bf16 rows, fp32 accum); epilogue
// hb = bf16( relu(nd*acc + bias) * (mode ? ns : 1) ).
__global__ __launch_bounds__(256) void agg128_kernel(const ushort* __restrict__ xb,
        const int* __restrict__ row_ptr, const int* __restrict__ col,
        const float* __restrict__ bias, const float* __restrict__ norm_dst,
        const float* __restrict__ norm_src, ushort* __restrict__ out, int n, int mode) {
    int wid  = (blockIdx.x * blockDim.x + threadIdx.x) >> 6;
    int lane = threadIdx.x & 63;
    if (wid >= n) return;
    int start = row_ptr[wid], end = row_ptr[wid + 1];
    int quarter = lane >> 4, l4 = lane & 15;
    float acc[8];
    #pragma unroll
    for (int i = 0; i < 8; ++i) acc[i] = 0.f;
    for (int b = start; b < end; b += 64) {
        int m = end - b; if (m > 64) m = 64;
        int u = 0;
        if (lane < m) u = col[b + lane];
        for (int j = 0; j < m; j += 4) {
            int jj = j + quarter;
            int uu = __shfl(u, jj);
            if (jj < m) {
                const uint4 v = *reinterpret_cast<const uint4*>(xb + (size_t)uu * 128 + 8 * l4);
                float f0, f1;
                unpack2(v.x, f0, f1); acc[0] += f0; acc[1] += f1;
                unpack2(v.y, f0, f1); acc[2] += f0; acc[3] += f1;
                unpack2(v.z, f0, f1); acc[4] += f0; acc[5] += f1;
                unpack2(v.w, f0, f1); acc[6] += f0; acc[7] += f1;
            }
        }
    }
    #pragma unroll
    for (int i = 0; i < 8; ++i) {
        acc[i] += __shfl_xor(acc[i], 16);
        acc[i] += __shfl_xor(acc[i], 32);
    }
    if (lane < 16) {
        float nd = norm_dst[wid];
        float sc = mode ? norm_src[wid] : 1.f;
        const float* bp = bias + 8 * lane;
        unsigned p[4];
        #pragma unroll
        for (int i = 0; i < 4; ++i) {
            float lo = fmaxf(fmaf(nd, acc[2 * i],     bp[2 * i]),     0.f) * sc;
            float hi = fmaxf(fmaf(nd, acc[2 * i + 1], bp[2 * i + 1]), 0.f) * sc;
            p[i] = (unsigned)f2bf(lo) | ((unsigned)f2bf(hi) << 16);
        }
        *reinterpret_cast<uint4*>(out + (size_t)wid * 128 + 8 * lane) =
            make_uint4(p[0], p[1], p[2], p[3]);
    }
}

// out[v][c] = norm_dst[v] * sum_{u->v} yb[u][c] + b3[c], c < 40.
__global__ __launch_bounds__(256) void agg40_kernel(const ushort* __restrict__ yb,
        const int* __restrict__ row_ptr, const int* __restrict__ col,
        const float* __restrict__ norm_dst, const float* __restrict__ b3,
        float* __restrict__ out, int n) {
    int wid  = (blockIdx.x * blockDim.x + threadIdx.x) >> 6;
    int lane = threadIdx.x & 63;
    if (wid >= n) return;
    int start = row_ptr[wid], end = row_ptr[wid + 1];
    int oct = lane >> 3, l8 = lane & 7;
    float acc[8];
    #pragma unroll
    for (int i = 0; i < 8; ++i) acc[i] = 0.f;
    for (int b = start; b < end; b += 64) {
        int m = end - b; if (m > 64) m = 64;
        int u = 0;
        if (lane < m) u = col[b + lane];
        for (int j = 0; j < m; j += 8) {
            int jj = j + oct;
            int uu = __shfl(u, jj);
            if (jj < m) {
                const uint4 v = *reinterpret_cast<const uint4*>(yb + (size_t)uu * 64 + 8 * l8);
                float f0, f1;
                unpack2(v.x, f0, f1); acc[0] += f0; acc[1] += f1;
                unpack2(v.y, f0, f1); acc[2] += f0; acc[3] += f1;
                unpack2(v.z, f0, f1); acc[4] += f0; acc[5] += f1;
                unpack2(v.w, f0, f1); acc[6] += f0; acc[7] += f1;
            }
        }
    }
    #pragma unroll
    for (int i = 0; i < 8; ++i) {
        acc[i] += __shfl_xor(acc[i], 8);
        acc[i] += __shfl_xor(acc[i], 16);
        acc[i] += __shfl_xor(acc[i], 32);
    }
    if (lane < 5) {
        float nd = norm_dst[wid];
        const float* bp = b3 + 8 * lane;
        float* op = out + (size_t)wid * 40 + 8 * lane;
        float4 o0, o1;
        o0.x = fmaf(nd, acc[0], bp[0]); o0.y = fmaf(nd, acc[1], bp[1]);
        o0.z = fmaf(nd, acc[2], bp[2]); o0.w = fmaf(nd, acc[3], bp[3]);
        o1.x = fmaf(nd, acc[4], bp[4]); o1.y = fmaf(nd, acc[5], bp[5]);
        o1.z = fmaf(nd, acc[6], bp[6]); o1.w = fmaf(nd, acc[7], bp[7]);
        *reinterpret_cast<float4*>(op)     = o0;
        *reinterpret_cast<float4*>(op + 4) = o1;
    }
}

extern "C" void kernel_launch(void* const* d_in, const int* in_sizes, int n_in,
                              void* d_out, int out_size, void* d_ws, size_t ws_size,
                              hipStream_t stream) {
    const float* features = (const float*)d_in[0];
    const int*   ei       = (const int*)d_in[1];
    const float* W1 = (const float*)d_in[2];
    const float* b1 = (const float*)d_in[3];
    const float* W2 = (const float*)d_in[4];
    const float* b2 = (const float*)d_in[5];
    const float* W3 = (const float*)d_in[6];
    const float* b3 = (const float*)d_in[7];

    const int n = in_sizes[0] / 128;
    const int E = in_sizes[1] / 2;

    const int nblk1 = (E + EPB - 1) / EPB;
    const int NB    = (n + 255) >> 8;
    const int L     = NB * nblk1;
    const int L2    = 2 * L;
    const int sb2   = (L2 + SCAN_CHUNK - 1) / SCAN_CHUNK;

    char* w = (char*)d_ws;
    auto alloc = [&](size_t bytes) {
        char* p = w;
        w += (bytes + 255) & ~(size_t)255;
        return p;
    };
    int*    hist_all = (int*)   alloc((size_t)L2 * 4);
    int*    partials = (int*)   alloc((size_t)256 * 4);
    float*  norm_src = (float*) alloc((size_t)n * 4);
    float*  norm_dst = (float*) alloc((size_t)n * 4);
    int*    row_ptr  = (int*)   alloc((size_t)(n + 1) * 4);
    int*    col      = (int*)   alloc((size_t)E * 4);
    ushort* fb       = (ushort*)alloc((size_t)n * 128 * 2);  // bf16 features
    ushort* xb       = (ushort*)alloc((size_t)n * 128 * 2);  // pre-agg table; yb aliases
    ushort* hb       = (ushort*)alloc((size_t)n * 128 * 2);  // activated table; CSR scratch aliases
    ushort* W1f      = (ushort*)alloc((size_t)16384 * 2);
    ushort* W2f      = (ushort*)alloc((size_t)16384 * 2);
    ushort* W3f      = (ushort*)alloc((size_t)8192 * 2);

    // CSR-build scratch aliases hb (consumed by bucket before agg128 writes hb).
    char* scr = (char*)hb;
    ushort*        rankD = (ushort*)scr;                 scr += ((size_t)E * 2 + 255) & ~(size_t)255;
    ushort*        rankS = (ushort*)scr;                 scr += ((size_t)E * 2 + 255) & ~(size_t)255;
    unsigned*      packD = (unsigned*)scr;               scr += ((size_t)E * 4 + 255) & ~(size_t)255;
    unsigned char* srcb  = (unsigned char*)scr;
    ushort* yb = xb;   // yb (n*64) aliases xb; xb consumed by agg128 #2 before mm3 writes yb

    int mmb = (n + 63) / 64;       // 4 waves x 16 rows
    int ab  = (n + 3) / 4;
    int cvb = (n * 32 + 255) / 256;

    prep_w_kernel<<<20, 256, 0, stream>>>(W1, W2, W3, W1f, W2f, W3f);
    cvt_kernel<<<cvb, 256, 0, stream>>>(features, fb, n * 32);
    hist_rank_kernel<<<nblk1, 256, 0, stream>>>(ei, E, nblk1, NB, hist_all, rankD, rankS);
    scanA_kernel<<<sb2, 256, 0, stream>>>(hist_all, L2, partials);
    scanB_kernel<<<1, 256, 0, stream>>>(partials, sb2);
    scanC_kernel<<<sb2, 256, 0, stream>>>(hist_all, L2, partials);
    scatter_part_kernel<<<nblk1, 256, 0, stream>>>(ei, E, nblk1, NB, hist_all,
                                                   rankD, rankS, packD, srcb);
    bucket_kernel<<<2 * NB, 256, 0, stream>>>(packD, srcb, hist_all, nblk1, NB, n, E,
                                              row_ptr, col, norm_src, norm_dst);
    mm_mfma_kernel<8, 1><<<mmb, 256, 0, stream>>>(fb, W1f, norm_src, xb, n);
    agg128_kernel<<<ab, 256, 0, stream>>>(xb, row_ptr, col, b1, norm_dst, norm_src,
                                          hb, n, 0);
    mm_mfma_kernel<8, 1><<<mmb, 256, 0, stream>>>(hb, W2f, norm_src, xb, n);
    agg128_kernel<<<ab, 256, 0, stream>>>(xb, row_ptr, col, b2, norm_dst, norm_src,
                                          hb, n, 1);
    mm_mfma_kernel<4, 0><<<mmb, 256, 0, stream>>>(hb, W3f, nullptr, yb, n);
    agg40_kernel<<<ab, 256, 0, stream>>>(yb, row_ptr, col, norm_dst, b3, (float*)d_out, n);
}

// Round 15
// 178.516 us; speedup vs baseline: 1.3731x; 1.0820x over previous
//
#include <hip/hip_runtime.h>

// GCN 3-layer forward on MI355X.
// CSR build WITHOUT global atomics; all matmuls on MFMA; minimized dispatch
// count (11): independent work fused into heterogeneous dispatches.
//   D1: hist_rank (196 blk) + prep_w (20 blk)
//   D2-4: hierarchical scan of bucket histograms
//   D5: scatter_part (196) + mm1 (fp32-in, raw epilogue)   [mm1 indep of CSR]
//   D6: bucket -> row_ptr/col/norms
//   D7: agg128 #1 (per-edge ns scale) -> hb = bf16(relu(nd*acc+b1))
//   D8: mm2 -> xb = bf16(ns*(hb@W2))
//   D9: agg128 #2 (plain) -> hb = bf16(relu(nd*acc+b2)*ns)
//   D10: mm3 -> yb = bf16(hb@W3) padded 40->64
//   D11: agg40 -> out fp32

#define EPB 4096
#define SCAN_CHUNK 4096

typedef short v8s __attribute__((ext_vector_type(8)));
typedef float v4f __attribute__((ext_vector_type(4)));

__device__ __forceinline__ ushort f2bf(float f) {
    unsigned u = __float_as_uint(f);
    unsigned r = (u + 0x7fffu + ((u >> 16) & 1u)) >> 16;  // RN-even
    return (ushort)r;
}
__device__ __forceinline__ void unpack2(unsigned w, float& lo, float& hi) {
    lo = __uint_as_float(w << 16);
    hi = __uint_as_float(w & 0xffff0000u);
}

// ---------------- D1: hist_rank + prep_w (fused) ----------------
__global__ __launch_bounds__(256) void front_kernel(const int* __restrict__ ei, int E,
        int nblk1, int NB, int* __restrict__ hist_all,
        ushort* __restrict__ rankD, ushort* __restrict__ rankS,
        const float* __restrict__ W1, const float* __restrict__ W2,
        const float* __restrict__ W3,
        ushort* __restrict__ W1f, ushort* __restrict__ W2f, ushort* __restrict__ W3f) {
    __shared__ int hd[512];
    __shared__ int hs[512];
    int t = threadIdx.x;
    if ((int)blockIdx.x >= nblk1) {
        // prep_w role: swizzle W into MFMA B-frag layout, bf16.
        int idx = ((int)blockIdx.x - nblk1) * 256 + t;
        const float* W; ushort* Wf; int Dout, NF, base;
        if (idx < 2048)      { W = W1; Wf = W1f; Dout = 128; NF = 8; base = idx; }
        else if (idx < 4096) { W = W2; Wf = W2f; Dout = 128; NF = 8; base = idx - 2048; }
        else if (idx < 5120) { W = W3; Wf = W3f; Dout = 40;  NF = 4; base = idx - 4096; }
        else return;
        int lane = base & 63;
        int f = (base >> 6) % NF;
        int ks = base / (64 * NF);
        int c = f * 16 + (lane & 15);
        int kbase = ks * 32 + (lane >> 4) * 8;
        unsigned p[4];
        #pragma unroll
        for (int j = 0; j < 4; ++j) {
            float wlo = (c < Dout) ? W[(size_t)(kbase + 2 * j) * Dout + c] : 0.f;
            float whi = (c < Dout) ? W[(size_t)(kbase + 2 * j + 1) * Dout + c] : 0.f;
            p[j] = (unsigned)f2bf(wlo) | ((unsigned)f2bf(whi) << 16);
        }
        *reinterpret_cast<uint4*>(Wf + (size_t)base * 8) = make_uint4(p[0], p[1], p[2], p[3]);
        return;
    }
    int blk = blockIdx.x;
    for (int i = t; i < 512; i += 256) { hd[i] = 0; hs[i] = 0; }
    __syncthreads();
    int base = blk * EPB;
    #pragma unroll
    for (int j = 0; j < 16; ++j) {
        int e = base + j * 256 + t;
        if (e < E) {
            int s = ei[e], d = ei[E + e];
            rankS[e] = (ushort)atomicAdd(&hs[s >> 8], 1);
            rankD[e] = (ushort)atomicAdd(&hd[d >> 8], 1);
        }
    }
    __syncthreads();
    int L = NB * nblk1;
    for (int b = t; b < NB; b += 256) {
        hist_all[b * nblk1 + blk]     = hd[b];
        hist_all[L + b * nblk1 + blk] = hs[b];
    }
}

// ---------------- scan ----------------
__global__ __launch_bounds__(256) void scanA_kernel(const int* __restrict__ data, int L2,
                                                    int* __restrict__ partials) {
    __shared__ int red[256];
    int t = threadIdx.x;
    int base = blockIdx.x * SCAN_CHUNK;
    int s = 0;
    for (int i = t; i < SCAN_CHUNK; i += 256) {
        int idx = base + i;
        if (idx < L2) s += data[idx];
    }
    red[t] = s;
    __syncthreads();
    for (int off = 128; off > 0; off >>= 1) {
        if (t < off) red[t] += red[t + off];
        __syncthreads();
    }
    if (t == 0) partials[blockIdx.x] = red[0];
}

__global__ __launch_bounds__(256) void scanB_kernel(int* __restrict__ partials, int nparts) {
    __shared__ int s[256];
    int t = threadIdx.x;
    s[t] = (t < nparts) ? partials[t] : 0;
    __syncthreads();
    for (int off = 1; off < 256; off <<= 1) {
        int v = (t >= off) ? s[t - off] : 0;
        __syncthreads();
        s[t] += v;
        __syncthreads();
    }
    if (t < nparts) partials[t] = s[t] - partials[t];
}

__global__ __launch_bounds__(256) void scanC_kernel(int* __restrict__ data, int L2,
                                                    const int* __restrict__ partials) {
    __shared__ int tsum[256];
    int t = threadIdx.x;
    int base = blockIdx.x * SCAN_CHUNK + t * 16;
    int local[16];
    int s = 0;
    #pragma unroll
    for (int i = 0; i < 16; ++i) {
        int idx = base + i;
        int v = (idx < L2) ? data[idx] : 0;
        local[i] = v;
        s += v;
    }
    tsum[t] = s;
    __syncthreads();
    for (int off = 1; off < 256; off <<= 1) {
        int v = (t >= off) ? tsum[t - off] : 0;
        __syncthreads();
        tsum[t] += v;
        __syncthreads();
    }
    int run = partials[blockIdx.x] + (t ? tsum[t - 1] : 0);
    #pragma unroll
    for (int i = 0; i < 16; ++i) {
        int idx = base + i;
        if (idx < L2) {
            data[idx] = run;
            run += local[i];
        }
    }
}

// ---------------- MFMA matmul (shared device fn) ----------------
// Wave computes 16 rows x NF*16 cols. A: X[row=lane&15][k=(lane>>4)*8+j];
// B pre-swizzled; C/D col=lane&15, row=(lane>>4)*4+reg (m89-verified).
template<int NF, int DO_NS, int FP32IN>
__device__ __forceinline__ void mm_body(const void* __restrict__ Xv,
        const ushort* __restrict__ Wf, const float* __restrict__ ns,
        ushort* __restrict__ out, int n, int blk, int wv, int lane) {
    int row0 = (blk * 4 + wv) * 16;
    if (row0 >= n) return;
    int arow = row0 + (lane & 15);
    if (arow >= n) arow = n - 1;  // clamp loads; stores guarded
    int kgrp = lane >> 4;
    const v8s* bp = reinterpret_cast<const v8s*>(Wf);
    v4f acc[NF];
    #pragma unroll
    for (int f = 0; f < NF; ++f) acc[f] = (v4f){0.f, 0.f, 0.f, 0.f};
    #pragma unroll
    for (int ks = 0; ks < 4; ++ks) {
        v8s a;
        if (FP32IN) {
            const float* xp = (const float*)Xv + (size_t)arow * 128 + (ks * 4 + kgrp) * 8;
            float4 lo = *reinterpret_cast<const float4*>(xp);
            float4 hi = *reinterpret_cast<const float4*>(xp + 4);
            a[0] = (short)f2bf(lo.x); a[1] = (short)f2bf(lo.y);
            a[2] = (short)f2bf(lo.z); a[3] = (short)f2bf(lo.w);
            a[4] = (short)f2bf(hi.x); a[5] = (short)f2bf(hi.y);
            a[6] = (short)f2bf(hi.z); a[7] = (short)f2bf(hi.w);
        } else {
            const v8s* ap = reinterpret_cast<const v8s*>((const ushort*)Xv + (size_t)arow * 128);
            a = ap[ks * 4 + kgrp];
        }
        #pragma unroll
        for (int f = 0; f < NF; ++f) {
            v8s b = bp[(ks * NF + f) * 64 + lane];
            acc[f] = __builtin_amdgcn_mfma_f32_16x16x32_bf16(a, b, acc[f], 0, 0, 0);
        }
    }
    int rbase = row0 + (lane >> 4) * 4;
    int ccol = lane & 15;
    constexpr int OS = NF * 16;
    #pragma unroll
    for (int r = 0; r < 4; ++r) {
        int gr = rbase + r;
        if (gr < n) {
            float s = DO_NS ? ns[gr] : 1.f;
            #pragma unroll
            for (int f = 0; f < NF; ++f)
                out[(size_t)gr * OS + f * 16 + ccol] = f2bf(s * acc[f][r]);
        }
    }
}

// ---------------- D5: scatter_part + mm1 (fused) ----------------
__global__ __launch_bounds__(256) void scatter_mm1_kernel(const int* __restrict__ ei, int E,
        int nblk1, int NB, const int* __restrict__ hist_all,
        const ushort* __restrict__ rankD, const ushort* __restrict__ rankS,
        unsigned* __restrict__ packD, unsigned char* __restrict__ srcb,
        const float* __restrict__ features, const ushort* __restrict__ W1f,
        ushort* __restrict__ xb, int n) {
    int t = threadIdx.x;
    if ((int)blockIdx.x >= nblk1) {
        int blk = (int)blockIdx.x - nblk1;
        mm_body<8, 0, 1>(features, W1f, nullptr, xb, n, blk, t >> 6, t & 63);
        return;
    }
    int blk = blockIdx.x;
    int base = blk * EPB;
    int L = NB * nblk1;
    #pragma unroll
    for (int j = 0; j < 16; ++j) {
        int e = base + j * 256 + t;
        if (e < E) {
            int s = ei[e], d = ei[E + e];
            int posD = hist_all[(d >> 8) * nblk1 + blk] + (int)rankD[e];
            packD[posD] = ((unsigned)(d & 255) << 24) | (unsigned)s;
            int posS = hist_all[L + (s >> 8) * nblk1 + blk] - E + (int)rankS[e];
            srcb[posS] = (unsigned char)(s & 255);
        }
    }
}

// ---------------- D6: bucket ----------------
__global__ __launch_bounds__(256) void bucket_kernel(const unsigned* __restrict__ packD,
        const unsigned char* __restrict__ srcb, const int* __restrict__ hist_all,
        int nblk1, int NB, int n, int E,
        int* __restrict__ row_ptr, int* __restrict__ col,
        float* __restrict__ norm_src, float* __restrict__ norm_dst) {
    int t = threadIdx.x;
    __shared__ int cnt[256];
    __shared__ int incl[256];
    __shared__ int cur[256];
    if ((int)blockIdx.x < NB) {
        int B = blockIdx.x;
        int s0 = hist_all[B * nblk1];
        int s1 = (B + 1 < NB) ? hist_all[(B + 1) * nblk1] : E;
        cnt[t] = 0;
        __syncthreads();
        for (int i = s0 + t; i < s1; i += 256)
            atomicAdd(&cnt[packD[i] >> 24], 1);
        __syncthreads();
        int v = cnt[t];
        incl[t] = v;
        __syncthreads();
        for (int off = 1; off < 256; off <<= 1) {
            int w = (t >= off) ? incl[t - off] : 0;
            __syncthreads();
            incl[t] += w;
            __syncthreads();
        }
        int excl = incl[t] - v;
        cur[t] = excl;
        int node = B * 256 + t;
        if (node < n) {
            row_ptr[node] = s0 + excl;
            norm_dst[node] = rsqrtf((float)(v > 0 ? v : 1));
        }
        if (B == NB - 1 && t == 0) row_ptr[n] = E;
        __syncthreads();
        for (int i = s0 + t; i < s1; i += 256) {
            unsigned p = packD[i];
            int r = atomicAdd(&cur[p >> 24], 1);
            col[s0 + r] = (int)(p & 0xFFFFFFu);
        }
    } else {
        int B = (int)blockIdx.x - NB;
        int L = NB * nblk1;
        int s0 = hist_all[L + B * nblk1] - E;
        int s1 = (B + 1 < NB) ? (hist_all[L + (B + 1) * nblk1] - E) : E;
        cnt[t] = 0;
        __syncthreads();
        for (int i = s0 + t; i < s1; i += 256)
            atomicAdd(&cnt[srcb[i]], 1);
        __syncthreads();
        int node = B * 256 + t;
        if (node < n) {
            int v = cnt[t];
            norm_src[node] = rsqrtf((float)(v > 0 ? v : 1));
        }
    }
}

// ---------------- MFMA mm standalone dispatches ----------------
template<int NF, int DO_NS>
__global__ __launch_bounds__(256) void mm_mfma_kernel(const ushort* __restrict__ X,
        const ushort* __restrict__ Wf, const float* __restrict__ ns,
        ushort* __restrict__ out, int n) {
    int t = threadIdx.x;
    mm_body<NF, DO_NS, 0>(X, Wf, ns, out, n, (int)blockIdx.x, t >> 6, t & 63);
}

// ---------------- aggregation ----------------
// One wave/node: acc = sum_{u->v} [ns[u] *] xb[u][:] (bf16 rows, fp32 accum);
// epilogue hb = bf16( relu(nd*acc + bias) * (MODE_NS ? ns : 1) ).
template<int EDGE_NS, int MODE_NS>
__global__ __launch_bounds__(256) void agg128_kernel(const ushort* __restrict__ xb,
        const int* __restrict__ row_ptr, const int* __restrict__ col,
        const float* __restrict__ bias, const float* __restrict__ norm_dst,
        const float* __restrict__ norm_src, ushort* __restrict__ out, int n) {
    int wid  = (blockIdx.x * blockDim.x + threadIdx.x) >> 6;
    int lane = threadIdx.x & 63;
    if (wid >= n) return;
    int start = row_ptr[wid], end = row_ptr[wid + 1];
    int quarter = lane >> 4, l4 = lane & 15;
    float acc[8];
    #pragma unroll
    for (int i = 0; i < 8; ++i) acc[i] = 0.f;
    for (int b = start; b < end; b += 64) {
        int m = end - b; if (m > 64) m = 64;
        int u = 0; float s = 1.f;
        if (lane < m) {
            u = col[b + lane];
            if (EDGE_NS) s = norm_src[u];
        }
        for (int j = 0; j < m; j += 4) {
            int jj = j + quarter;
            int uu = __shfl(u, jj);
            float ss = EDGE_NS ? __shfl(s, jj) : 1.f;
            if (jj < m) {
                const uint4 v = *reinterpret_cast<const uint4*>(xb + (size_t)uu * 128 + 8 * l4);
                float f0, f1;
                if (EDGE_NS) {
                    unpack2(v.x, f0, f1); acc[0] = fmaf(ss, f0, acc[0]); acc[1] = fmaf(ss, f1, acc[1]);
                    unpack2(v.y, f0, f1); acc[2] = fmaf(ss, f0, acc[2]); acc[3] = fmaf(ss, f1, acc[3]);
                    unpack2(v.z, f0, f1); acc[4] = fmaf(ss, f0, acc[4]); acc[5] = fmaf(ss, f1, acc[5]);
                    unpack2(v.w, f0, f1); acc[6] = fmaf(ss, f0, acc[6]); acc[7] = fmaf(ss, f1, acc[7]);
                } else {
                    unpack2(v.x, f0, f1); acc[0] += f0; acc[1] += f1;
                    unpack2(v.y, f0, f1); acc[2] += f0; acc[3] += f1;
                    unpack2(v.z, f0, f1); acc[4] += f0; acc[5] += f1;
                    unpack2(v.w, f0, f1); acc[6] += f0; acc[7] += f1;
                }
            }
        }
    }
    #pragma unroll
    for (int i = 0; i < 8; ++i) {
        acc[i] += __shfl_xor(acc[i], 16);
        acc[i] += __shfl_xor(acc[i], 32);
    }
    if (lane < 16) {
        float nd = norm_dst[wid];
        float sc = MODE_NS ? norm_src[wid] : 1.f;
        const float* bp = bias + 8 * lane;
        unsigned p[4];
        #pragma unroll
        for (int i = 0; i < 4; ++i) {
            float lo = fmaxf(fmaf(nd, acc[2 * i],     bp[2 * i]),     0.f) * sc;
            float hi = fmaxf(fmaf(nd, acc[2 * i + 1], bp[2 * i + 1]), 0.f) * sc;
            p[i] = (unsigned)f2bf(lo) | ((unsigned)f2bf(hi) << 16);
        }
        *reinterpret_cast<uint4*>(out + (size_t)wid * 128 + 8 * lane) =
            make_uint4(p[0], p[1], p[2], p[3]);
    }
}

// out[v][c] = norm_dst[v] * sum_{u->v} yb[u][c] + b3[c], c < 40.
__global__ __launch_bounds__(256) void agg40_kernel(const ushort* __restrict__ yb,
        const int* __restrict__ row_ptr, const int* __restrict__ col,
        const float* __restrict__ norm_dst, const float* __restrict__ b3,
        float* __restrict__ out, int n) {
    int wid  = (blockIdx.x * blockDim.x + threadIdx.x) >> 6;
    int lane = threadIdx.x & 63;
    if (wid >= n) return;
    int start = row_ptr[wid], end = row_ptr[wid + 1];
    int oct = lane >> 3, l8 = lane & 7;
    float acc[8];
    #pragma unroll
    for (int i = 0; i < 8; ++i) acc[i] = 0.f;
    for (int b = start; b < end; b += 64) {
        int m = end - b; if (m > 64) m = 64;
        int u = 0;
        if (lane < m) u = col[b + lane];
        for (int j = 0; j < m; j += 8) {
            int jj = j + oct;
            int uu = __shfl(u, jj);
            if (jj < m) {
                const uint4 v = *reinterpret_cast<const uint4*>(yb + (size_t)uu * 64 + 8 * l8);
                float f0, f1;
                unpack2(v.x, f0, f1); acc[0] += f0; acc[1] += f1;
                unpack2(v.y, f0, f1); acc[2] += f0; acc[3] += f1;
                unpack2(v.z, f0, f1); acc[4] += f0; acc[5] += f1;
                unpack2(v.w, f0, f1); acc[6] += f0; acc[7] += f1;
            }
        }
    }
    #pragma unroll
    for (int i = 0; i < 8; ++i) {
        acc[i] += __shfl_xor(acc[i], 8);
        acc[i] += __shfl_xor(acc[i], 16);
        acc[i] += __shfl_xor(acc[i], 32);
    }
    if (lane < 5) {
        float nd = norm_dst[wid];
        const float* bp = b3 + 8 * lane;
        float* op = out + (size_t)wid * 40 + 8 * lane;
        float4 o0, o1;
        o0.x = fmaf(nd, acc[0], bp[0]); o0.y = fmaf(nd, acc[1], bp[1]);
        o0.z = fmaf(nd, acc[2], bp[2]); o0.w = fmaf(nd, acc[3], bp[3]);
        o1.x = fmaf(nd, acc[4], bp[4]); o1.y = fmaf(nd, acc[5], bp[5]);
        o1.z = fmaf(nd, acc[6], bp[6]); o1.w = fmaf(nd, acc[7], bp[7]);
        *reinterpret_cast<float4*>(op)     = o0;
        *reinterpret_cast<float4*>(op + 4) = o1;
    }
}

extern "C" void kernel_launch(void* const* d_in, const int* in_sizes, int n_in,
                              void* d_out, int out_size, void* d_ws, size_t ws_size,
                              hipStream_t stream) {
    const float* features = (const float*)d_in[0];
    const int*   ei       = (const int*)d_in[1];
    const float* W1 = (const float*)d_in[2];
    const float* b1 = (const float*)d_in[3];
    const float* W2 = (const float*)d_in[4];
    const float* b2 = (const float*)d_in[5];
    const float* W3 = (const float*)d_in[6];
    const float* b3 = (const float*)d_in[7];

    const int n = in_sizes[0] / 128;
    const int E = in_sizes[1] / 2;

    const int nblk1 = (E + EPB - 1) / EPB;
    const int NB    = (n + 255) >> 8;
    const int L     = NB * nblk1;
    const int L2    = 2 * L;
    const int sb2   = (L2 + SCAN_CHUNK - 1) / SCAN_CHUNK;

    char* w = (char*)d_ws;
    auto alloc = [&](size_t bytes) {
        char* p = w;
        w += (bytes + 255) & ~(size_t)255;
        return p;
    };
    int*    hist_all = (int*)   alloc((size_t)L2 * 4);
    int*    partials = (int*)   alloc((size_t)256 * 4);
    float*  norm_src = (float*) alloc((size_t)n * 4);
    float*  norm_dst = (float*) alloc((size_t)n * 4);
    int*    row_ptr  = (int*)   alloc((size_t)(n + 1) * 4);
    int*    col      = (int*)   alloc((size_t)E * 4);
    ushort* xb       = (ushort*)alloc((size_t)n * 128 * 2);  // pre-agg table; yb aliases
    ushort* hb       = (ushort*)alloc((size_t)n * 128 * 2);  // activated table; CSR scratch aliases
    ushort* W1f      = (ushort*)alloc((size_t)16384 * 2);
    ushort* W2f      = (ushort*)alloc((size_t)16384 * 2);
    ushort* W3f      = (ushort*)alloc((size_t)8192 * 2);

    // CSR-build scratch aliases hb (consumed by bucket before agg128 #1 writes hb).
    char* scr = (char*)hb;
    ushort*        rankD = (ushort*)scr;                 scr += ((size_t)E * 2 + 255) & ~(size_t)255;
    ushort*        rankS = (ushort*)scr;                 scr += ((size_t)E * 2 + 255) & ~(size_t)255;
    unsigned*      packD = (unsigned*)scr;               scr += ((size_t)E * 4 + 255) & ~(size_t)255;
    unsigned char* srcb  = (unsigned char*)scr;
    ushort* yb = xb;   // yb (n*64) aliases xb; xb consumed by agg128 #2 before mm3 writes yb

    int mmb = (n + 63) / 64;       // 4 waves x 16 rows
    int ab  = (n + 3) / 4;

    front_kernel<<<nblk1 + 20, 256, 0, stream>>>(ei, E, nblk1, NB, hist_all,
                                                 rankD, rankS, W1, W2, W3, W1f, W2f, W3f);
    scanA_kernel<<<sb2, 256, 0, stream>>>(hist_all, L2, partials);
    scanB_kernel<<<1, 256, 0, stream>>>(partials, sb2);
    scanC_kernel<<<sb2, 256, 0, stream>>>(hist_all, L2, partials);
    scatter_mm1_kernel<<<nblk1 + mmb, 256, 0, stream>>>(ei, E, nblk1, NB, hist_all,
                                                        rankD, rankS, packD, srcb,
                                                        features, W1f, xb, n);
    bucket_kernel<<<2 * NB, 256, 0, stream>>>(packD, srcb, hist_all, nblk1, NB, n, E,
                                              row_ptr, col, norm_src, norm_dst);
    agg128_kernel<1, 0><<<ab, 256, 0, stream>>>(xb, row_ptr, col, b1, norm_dst,
                                                norm_src, hb, n);
    mm_mfma_kernel<8, 1><<<mmb, 256, 0, stream>>>(hb, W2f, norm_src, xb, n);
    agg128_kernel<0, 1><<<ab, 256, 0, stream>>>(xb, row_ptr, col, b2, norm_dst,
                                                norm_src, hb, n);
    mm_mfma_kernel<4, 0><<<mmb, 256, 0, stream>>>(hb, W3f, nullptr, yb, n);
    agg40_kernel<<<ab, 256, 0, stream>>>(yb, row_ptr, col, norm_dst, b3, (float*)d_out, n);
}

// Round 16
// 164.103 us; speedup vs baseline: 1.4937x; 1.0878x over previous
//
#include <hip/hip_runtime.h>

// GCN 3-layer forward on MI355X.
// CSR build WITHOUT global atomics; all matmuls on MFMA; 9 dispatches:
//   D1: hist_rank + prep_w        D2-4: hierarchical scan
//   D5: scatter_part + mm1 (fp32->bf16 A in-reg) -> xb1
//   D6: bucket -> row_ptr/col/norms
//   D7: FUSED agg(xb1, edge-ns)+act(b1,nd) -> LDS -> MFMA @W2 *ns -> xb2
//   D8: FUSED agg(xb2)+act(b2,nd)*ns -> LDS -> MFMA @W3 -> yb (pad 40->64)
//   D9: agg40 -> out fp32
// Fusion passes activated rows through LDS (16x136 bf16, 2-way-bank-free),
// deleting the hb global round-trip entirely. Numerics bit-identical to r15.

#define EPB 4096
#define SCAN_CHUNK 4096

typedef short v8s __attribute__((ext_vector_type(8)));
typedef float v4f __attribute__((ext_vector_type(4)));

__device__ __forceinline__ ushort f2bf(float f) {
    unsigned u = __float_as_uint(f);
    unsigned r = (u + 0x7fffu + ((u >> 16) & 1u)) >> 16;  // RN-even
    return (ushort)r;
}
__device__ __forceinline__ void unpack2(unsigned w, float& lo, float& hi) {
    lo = __uint_as_float(w << 16);
    hi = __uint_as_float(w & 0xffff0000u);
}

// ---------------- D1: hist_rank + prep_w (fused) ----------------
__global__ __launch_bounds__(256) void front_kernel(const int* __restrict__ ei, int E,
        int nblk1, int NB, int* __restrict__ hist_all,
        ushort* __restrict__ rankD, ushort* __restrict__ rankS,
        const float* __restrict__ W1, const float* __restrict__ W2,
        const float* __restrict__ W3,
        ushort* __restrict__ W1f, ushort* __restrict__ W2f, ushort* __restrict__ W3f) {
    __shared__ int hd[512];
    __shared__ int hs[512];
    int t = threadIdx.x;
    if ((int)blockIdx.x >= nblk1) {
        int idx = ((int)blockIdx.x - nblk1) * 256 + t;
        const float* W; ushort* Wf; int Dout, NF, base;
        if (idx < 2048)      { W = W1; Wf = W1f; Dout = 128; NF = 8; base = idx; }
        else if (idx < 4096) { W = W2; Wf = W2f; Dout = 128; NF = 8; base = idx - 2048; }
        else if (idx < 5120) { W = W3; Wf = W3f; Dout = 40;  NF = 4; base = idx - 4096; }
        else return;
        int lane = base & 63;
        int f = (base >> 6) % NF;
        int ks = base / (64 * NF);
        int c = f * 16 + (lane & 15);
        int kbase = ks * 32 + (lane >> 4) * 8;
        unsigned p[4];
        #pragma unroll
        for (int j = 0; j < 4; ++j) {
            float wlo = (c < Dout) ? W[(size_t)(kbase + 2 * j) * Dout + c] : 0.f;
            float whi = (c < Dout) ? W[(size_t)(kbase + 2 * j + 1) * Dout + c] : 0.f;
            p[j] = (unsigned)f2bf(wlo) | ((unsigned)f2bf(whi) << 16);
        }
        *reinterpret_cast<uint4*>(Wf + (size_t)base * 8) = make_uint4(p[0], p[1], p[2], p[3]);
        return;
    }
    int blk = blockIdx.x;
    for (int i = t; i < 512; i += 256) { hd[i] = 0; hs[i] = 0; }
    __syncthreads();
    int base = blk * EPB;
    #pragma unroll
    for (int j = 0; j < 16; ++j) {
        int e = base + j * 256 + t;
        if (e < E) {
            int s = ei[e], d = ei[E + e];
            rankS[e] = (ushort)atomicAdd(&hs[s >> 8], 1);
            rankD[e] = (ushort)atomicAdd(&hd[d >> 8], 1);
        }
    }
    __syncthreads();
    int L = NB * nblk1;
    for (int b = t; b < NB; b += 256) {
        hist_all[b * nblk1 + blk]     = hd[b];
        hist_all[L + b * nblk1 + blk] = hs[b];
    }
}

// ---------------- scan ----------------
__global__ __launch_bounds__(256) void scanA_kernel(const int* __restrict__ data, int L2,
                                                    int* __restrict__ partials) {
    __shared__ int red[256];
    int t = threadIdx.x;
    int base = blockIdx.x * SCAN_CHUNK;
    int s = 0;
    for (int i = t; i < SCAN_CHUNK; i += 256) {
        int idx = base + i;
        if (idx < L2) s += data[idx];
    }
    red[t] = s;
    __syncthreads();
    for (int off = 128; off > 0; off >>= 1) {
        if (t < off) red[t] += red[t + off];
        __syncthreads();
    }
    if (t == 0) partials[blockIdx.x] = red[0];
}

__global__ __launch_bounds__(256) void scanB_kernel(int* __restrict__ partials, int nparts) {
    __shared__ int s[256];
    int t = threadIdx.x;
    s[t] = (t < nparts) ? partials[t] : 0;
    __syncthreads();
    for (int off = 1; off < 256; off <<= 1) {
        int v = (t >= off) ? s[t - off] : 0;
        __syncthreads();
        s[t] += v;
        __syncthreads();
    }
    if (t < nparts) partials[t] = s[t] - partials[t];
}

__global__ __launch_bounds__(256) void scanC_kernel(int* __restrict__ data, int L2,
                                                    const int* __restrict__ partials) {
    __shared__ int tsum[256];
    int t = threadIdx.x;
    int base = blockIdx.x * SCAN_CHUNK + t * 16;
    int local[16];
    int s = 0;
    #pragma unroll
    for (int i = 0; i < 16; ++i) {
        int idx = base + i;
        int v = (idx < L2) ? data[idx] : 0;
        local[i] = v;
        s += v;
    }
    tsum[t] = s;
    __syncthreads();
    for (int off = 1; off < 256; off <<= 1) {
        int v = (t >= off) ? tsum[t - off] : 0;
        __syncthreads();
        tsum[t] += v;
        __syncthreads();
    }
    int run = partials[blockIdx.x] + (t ? tsum[t - 1] : 0);
    #pragma unroll
    for (int i = 0; i < 16; ++i) {
        int idx = base + i;
        if (idx < L2) {
            data[idx] = run;
            run += local[i];
        }
    }
}

// ---------------- MFMA matmul body (global-A variant, for mm1) ----------------
template<int NF, int DO_NS, int FP32IN>
__device__ __forceinline__ void mm_body(const void* __restrict__ Xv,
        const ushort* __restrict__ Wf, const float* __restrict__ ns,
        ushort* __restrict__ out, int n, int blk, int wv, int lane) {
    int row0 = (blk * 4 + wv) * 16;
    if (row0 >= n) return;
    int arow = row0 + (lane & 15);
    if (arow >= n) arow = n - 1;
    int kgrp = lane >> 4;
    const v8s* bp = reinterpret_cast<const v8s*>(Wf);
    v4f acc[NF];
    #pragma unroll
    for (int f = 0; f < NF; ++f) acc[f] = (v4f){0.f, 0.f, 0.f, 0.f};
    #pragma unroll
    for (int ks = 0; ks < 4; ++ks) {
        v8s a;
        if (FP32IN) {
            const float* xp = (const float*)Xv + (size_t)arow * 128 + (ks * 4 + kgrp) * 8;
            float4 lo = *reinterpret_cast<const float4*>(xp);
            float4 hi = *reinterpret_cast<const float4*>(xp + 4);
            a[0] = (short)f2bf(lo.x); a[1] = (short)f2bf(lo.y);
            a[2] = (short)f2bf(lo.z); a[3] = (short)f2bf(lo.w);
            a[4] = (short)f2bf(hi.x); a[5] = (short)f2bf(hi.y);
            a[6] = (short)f2bf(hi.z); a[7] = (short)f2bf(hi.w);
        } else {
            const v8s* ap = reinterpret_cast<const v8s*>((const ushort*)Xv + (size_t)arow * 128);
            a = ap[ks * 4 + kgrp];
        }
        #pragma unroll
        for (int f = 0; f < NF; ++f) {
            v8s b = bp[(ks * NF + f) * 64 + lane];
            acc[f] = __builtin_amdgcn_mfma_f32_16x16x32_bf16(a, b, acc[f], 0, 0, 0);
        }
    }
    int rbase = row0 + (lane >> 4) * 4;
    int ccol = lane & 15;
    constexpr int OS = NF * 16;
    #pragma unroll
    for (int r = 0; r < 4; ++r) {
        int gr = rbase + r;
        if (gr < n) {
            float s = DO_NS ? ns[gr] : 1.f;
            #pragma unroll
            for (int f = 0; f < NF; ++f)
                out[(size_t)gr * OS + f * 16 + ccol] = f2bf(s * acc[f][r]);
        }
    }
}

// ---------------- D5: scatter_part + mm1 (fused) ----------------
__global__ __launch_bounds__(256) void scatter_mm1_kernel(const int* __restrict__ ei, int E,
        int nblk1, int NB, const int* __restrict__ hist_all,
        const ushort* __restrict__ rankD, const ushort* __restrict__ rankS,
        unsigned* __restrict__ packD, unsigned char* __restrict__ srcb,
        const float* __restrict__ features, const ushort* __restrict__ W1f,
        ushort* __restrict__ xb, int n) {
    int t = threadIdx.x;
    if ((int)blockIdx.x >= nblk1) {
        int blk = (int)blockIdx.x - nblk1;
        mm_body<8, 0, 1>(features, W1f, nullptr, xb, n, blk, t >> 6, t & 63);
        return;
    }
    int blk = blockIdx.x;
    int base = blk * EPB;
    int L = NB * nblk1;
    #pragma unroll
    for (int j = 0; j < 16; ++j) {
        int e = base + j * 256 + t;
        if (e < E) {
            int s = ei[e], d = ei[E + e];
            int posD = hist_all[(d >> 8) * nblk1 + blk] + (int)rankD[e];
            packD[posD] = ((unsigned)(d & 255) << 24) | (unsigned)s;
            int posS = hist_all[L + (s >> 8) * nblk1 + blk] - E + (int)rankS[e];
            srcb[posS] = (unsigned char)(s & 255);
        }
    }
}

// ---------------- D6: bucket ----------------
__global__ __launch_bounds__(256) void bucket_kernel(const unsigned* __restrict__ packD,
        const unsigned char* __restrict__ srcb, const int* __restrict__ hist_all,
        int nblk1, int NB, int n, int E,
        int* __restrict__ row_ptr, int* __restrict__ col,
        float* __restrict__ norm_src, float* __restrict__ norm_dst) {
    int t = threadIdx.x;
    __shared__ int cnt[256];
    __shared__ int incl[256];
    __shared__ int cur[256];
    if ((int)blockIdx.x < NB) {
        int B = blockIdx.x;
        int s0 = hist_all[B * nblk1];
        int s1 = (B + 1 < NB) ? hist_all[(B + 1) * nblk1] : E;
        cnt[t] = 0;
        __syncthreads();
        for (int i = s0 + t; i < s1; i += 256)
            atomicAdd(&cnt[packD[i] >> 24], 1);
        __syncthreads();
        int v = cnt[t];
        incl[t] = v;
        __syncthreads();
        for (int off = 1; off < 256; off <<= 1) {
            int w = (t >= off) ? incl[t - off] : 0;
            __syncthreads();
            incl[t] += w;
            __syncthreads();
        }
        int excl = incl[t] - v;
        cur[t] = excl;
        int node = B * 256 + t;
        if (node < n) {
            row_ptr[node] = s0 + excl;
            norm_dst[node] = rsqrtf((float)(v > 0 ? v : 1));
        }
        if (B == NB - 1 && t == 0) row_ptr[n] = E;
        __syncthreads();
        for (int i = s0 + t; i < s1; i += 256) {
            unsigned p = packD[i];
            int r = atomicAdd(&cur[p >> 24], 1);
            col[s0 + r] = (int)(p & 0xFFFFFFu);
        }
    } else {
        int B = (int)blockIdx.x - NB;
        int L = NB * nblk1;
        int s0 = hist_all[L + B * nblk1] - E;
        int s1 = (B + 1 < NB) ? (hist_all[L + (B + 1) * nblk1] - E) : E;
        cnt[t] = 0;
        __syncthreads();
        for (int i = s0 + t; i < s1; i += 256)
            atomicAdd(&cnt[srcb[i]], 1);
        __syncthreads();
        int node = B * 256 + t;
        if (node < n) {
            int v = cnt[t];
            norm_src[node] = rsqrtf((float)(v > 0 ? v : 1));
        }
    }
}

// ---------------- D7/D8: FUSED agg + MFMA ----------------
// Block = 16 nodes. Wave wv aggregates nodes row0+wv*4..+3 (4 edges/iter),
// applies activation, writes bf16 row to LDS [16][136] (272B stride: 2-way
// bank aliasing only). Then MFMA: wave wv computes frags F=wv*FPW..+FPW-1
// (16 rows x FPW*16 cols) with A-frags read from LDS.
template<int EDGE_NS, int ACT_NS, int NF_TOT, int MM_NS, int PAD40>
__global__ __launch_bounds__(256) void aggmm_kernel(const ushort* __restrict__ xt,
        const int* __restrict__ row_ptr, const int* __restrict__ col,
        const float* __restrict__ bias, const float* __restrict__ norm_dst,
        const float* __restrict__ norm_src, const ushort* __restrict__ Wf,
        ushort* __restrict__ out, int n) {
    __shared__ ushort Xl[16][136];
    int t = threadIdx.x;
    int wv = t >> 6, lane = t & 63;
    int row0 = (int)blockIdx.x * 16;
    int quarter = lane >> 4, l4 = lane & 15;
    for (int i = 0; i < 4; ++i) {
        int vi = row0 + wv * 4 + i;
        int lrow = wv * 4 + i;
        if (vi < n) {
            int start = row_ptr[vi], end = row_ptr[vi + 1];
            float acc[8];
            #pragma unroll
            for (int q = 0; q < 8; ++q) acc[q] = 0.f;
            for (int b = start; b < end; b += 64) {
                int m = end - b; if (m > 64) m = 64;
                int u = 0; float s = 1.f;
                if (lane < m) {
                    u = col[b + lane];
                    if (EDGE_NS) s = norm_src[u];
                }
                for (int j = 0; j < m; j += 4) {
                    int jj = j + quarter;
                    int uu = __shfl(u, jj);
                    float ss = EDGE_NS ? __shfl(s, jj) : 1.f;
                    if (jj < m) {
                        const uint4 v = *reinterpret_cast<const uint4*>(xt + (size_t)uu * 128 + 8 * l4);
                        float f0, f1;
                        if (EDGE_NS) {
                            unpack2(v.x, f0, f1); acc[0] = fmaf(ss, f0, acc[0]); acc[1] = fmaf(ss, f1, acc[1]);
                            unpack2(v.y, f0, f1); acc[2] = fmaf(ss, f0, acc[2]); acc[3] = fmaf(ss, f1, acc[3]);
                            unpack2(v.z, f0, f1); acc[4] = fmaf(ss, f0, acc[4]); acc[5] = fmaf(ss, f1, acc[5]);
                            unpack2(v.w, f0, f1); acc[6] = fmaf(ss, f0, acc[6]); acc[7] = fmaf(ss, f1, acc[7]);
                        } else {
                            unpack2(v.x, f0, f1); acc[0] += f0; acc[1] += f1;
                            unpack2(v.y, f0, f1); acc[2] += f0; acc[3] += f1;
                            unpack2(v.z, f0, f1); acc[4] += f0; acc[5] += f1;
                            unpack2(v.w, f0, f1); acc[6] += f0; acc[7] += f1;
                        }
                    }
                }
            }
            #pragma unroll
            for (int q = 0; q < 8; ++q) {
                acc[q] += __shfl_xor(acc[q], 16);
                acc[q] += __shfl_xor(acc[q], 32);
            }
            if (lane < 16) {
                float nd = norm_dst[vi];
                float sc = ACT_NS ? norm_src[vi] : 1.f;
                const float* bp = bias + 8 * lane;
                unsigned p[4];
                #pragma unroll
                for (int q = 0; q < 4; ++q) {
                    float lo = fmaxf(fmaf(nd, acc[2 * q],     bp[2 * q]),     0.f) * sc;
                    float hi = fmaxf(fmaf(nd, acc[2 * q + 1], bp[2 * q + 1]), 0.f) * sc;
                    p[q] = (unsigned)f2bf(lo) | ((unsigned)f2bf(hi) << 16);
                }
                *reinterpret_cast<uint4*>(&Xl[lrow][8 * lane]) = make_uint4(p[0], p[1], p[2], p[3]);
            }
        } else if (lane < 16) {
            *reinterpret_cast<uint4*>(&Xl[lrow][8 * lane]) = make_uint4(0, 0, 0, 0);
        }
    }
    __syncthreads();
    constexpr int FPW = NF_TOT / 4;
    const v8s* bp = reinterpret_cast<const v8s*>(Wf);
    int kgrp = lane >> 4;
    v4f acc[FPW];
    #pragma unroll
    for (int f = 0; f < FPW; ++f) acc[f] = (v4f){0.f, 0.f, 0.f, 0.f};
    #pragma unroll
    for (int ks = 0; ks < 4; ++ks) {
        v8s a = *reinterpret_cast<const v8s*>(&Xl[lane & 15][(ks * 4 + kgrp) * 8]);
        #pragma unroll
        for (int f = 0; f < FPW; ++f) {
            int F = wv * FPW + f;
            v8s b = bp[(ks * NF_TOT + F) * 64 + lane];
            acc[f] = __builtin_amdgcn_mfma_f32_16x16x32_bf16(a, b, acc[f], 0, 0, 0);
        }
    }
    int rbase = row0 + (lane >> 4) * 4;
    int ccol = lane & 15;
    constexpr int OS = NF_TOT * 16;
    #pragma unroll
    for (int r = 0; r < 4; ++r) {
        int gr = rbase + r;
        if (gr < n) {
            float s = MM_NS ? norm_src[gr] : 1.f;
            #pragma unroll
            for (int f = 0; f < FPW; ++f) {
                int colo = (wv * FPW + f) * 16 + ccol;
                ushort val = f2bf(s * acc[f][r]);
                if (PAD40 && colo >= 40) val = 0;
                out[(size_t)gr * OS + colo] = val;
            }
        }
    }
}

// ---------------- D9: agg40 ----------------
__global__ __launch_bounds__(256) void agg40_kernel(const ushort* __restrict__ yb,
        const int* __restrict__ row_ptr, const int* __restrict__ col,
        const float* __restrict__ norm_dst, const float* __restrict__ b3,
        float* __restrict__ out, int n) {
    int wid  = (blockIdx.x * blockDim.x + threadIdx.x) >> 6;
    int lane = threadIdx.x & 63;
    if (wid >= n) return;
    int start = row_ptr[wid], end = row_ptr[wid + 1];
    int oct = lane >> 3, l8 = lane & 7;
    float acc[8];
    #pragma unroll
    for (int i = 0; i < 8; ++i) acc[i] = 0.f;
    for (int b = start; b < end; b += 64) {
        int m = end - b; if (m > 64) m = 64;
        int u = 0;
        if (lane < m) u = col[b + lane];
        for (int j = 0; j < m; j += 8) {
            int jj = j + oct;
            int uu = __shfl(u, jj);
            if (jj < m) {
                const uint4 v = *reinterpret_cast<const uint4*>(yb + (size_t)uu * 64 + 8 * l8);
                float f0, f1;
                unpack2(v.x, f0, f1); acc[0] += f0; acc[1] += f1;
                unpack2(v.y, f0, f1); acc[2] += f0; acc[3] += f1;
                unpack2(v.z, f0, f1); acc[4] += f0; acc[5] += f1;
                unpack2(v.w, f0, f1); acc[6] += f0; acc[7] += f1;
            }
        }
    }
    #pragma unroll
    for (int i = 0; i < 8; ++i) {
        acc[i] += __shfl_xor(acc[i], 8);
        acc[i] += __shfl_xor(acc[i], 16);
        acc[i] += __shfl_xor(acc[i], 32);
    }
    if (lane < 5) {
        float nd = norm_dst[wid];
        const float* bp = b3 + 8 * lane;
        float* op = out + (size_t)wid * 40 + 8 * lane;
        float4 o0, o1;
        o0.x = fmaf(nd, acc[0], bp[0]); o0.y = fmaf(nd, acc[1], bp[1]);
        o0.z = fmaf(nd, acc[2], bp[2]); o0.w = fmaf(nd, acc[3], bp[3]);
        o1.x = fmaf(nd, acc[4], bp[4]); o1.y = fmaf(nd, acc[5], bp[5]);
        o1.z = fmaf(nd, acc[6], bp[6]); o1.w = fmaf(nd, acc[7], bp[7]);
        *reinterpret_cast<float4*>(op)     = o0;
        *reinterpret_cast<float4*>(op + 4) = o1;
    }
}

extern "C" void kernel_launch(void* const* d_in, const int* in_sizes, int n_in,
                              void* d_out, int out_size, void* d_ws, size_t ws_size,
                              hipStream_t stream) {
    const float* features = (const float*)d_in[0];
    const int*   ei       = (const int*)d_in[1];
    const float* W1 = (const float*)d_in[2];
    const float* b1 = (const float*)d_in[3];
    const float* W2 = (const float*)d_in[4];
    const float* b2 = (const float*)d_in[5];
    const float* W3 = (const float*)d_in[6];
    const float* b3 = (const float*)d_in[7];

    const int n = in_sizes[0] / 128;
    const int E = in_sizes[1] / 2;

    const int nblk1 = (E + EPB - 1) / EPB;
    const int NB    = (n + 255) >> 8;
    const int L     = NB * nblk1;
    const int L2    = 2 * L;
    const int sb2   = (L2 + SCAN_CHUNK - 1) / SCAN_CHUNK;

    char* w = (char*)d_ws;
    auto alloc = [&](size_t bytes) {
        char* p = w;
        w += (bytes + 255) & ~(size_t)255;
        return p;
    };
    int*    hist_all = (int*)   alloc((size_t)L2 * 4);
    int*    partials = (int*)   alloc((size_t)256 * 4);
    float*  norm_src = (float*) alloc((size_t)n * 4);
    float*  norm_dst = (float*) alloc((size_t)n * 4);
    int*    row_ptr  = (int*)   alloc((size_t)(n + 1) * 4);
    int*    col      = (int*)   alloc((size_t)E * 4);
    ushort* xb1      = (ushort*)alloc((size_t)n * 128 * 2);  // mm1 output table
    ushort* xb2      = (ushort*)alloc((size_t)n * 128 * 2);  // fused-l2 output table
    char*   scratch  = (char*)  alloc((size_t)12 * E);       // CSR scratch; yb aliases after D6
    ushort* W1f      = (ushort*)alloc((size_t)16384 * 2);
    ushort* W2f      = (ushort*)alloc((size_t)16384 * 2);
    ushort* W3f      = (ushort*)alloc((size_t)8192 * 2);

    char* scr = scratch;
    ushort*        rankD = (ushort*)scr;                 scr += ((size_t)E * 2 + 255) & ~(size_t)255;
    ushort*        rankS = (ushort*)scr;                 scr += ((size_t)E * 2 + 255) & ~(size_t)255;
    unsigned*      packD = (unsigned*)scr;               scr += ((size_t)E * 4 + 255) & ~(size_t)255;
    unsigned char* srcb  = (unsigned char*)scr;
    ushort* yb = (ushort*)scratch;  // yb (n*64*2 = 6.4MB) reuses dead CSR scratch after D6

    int mmb = (n + 63) / 64;       // mm1 tiles (4 waves x 16 rows)
    int fb  = (n + 15) / 16;       // fused agg+mm blocks (16 nodes each)
    int ab  = (n + 3) / 4;

    front_kernel<<<nblk1 + 20, 256, 0, stream>>>(ei, E, nblk1, NB, hist_all,
                                                 rankD, rankS, W1, W2, W3, W1f, W2f, W3f);
    scanA_kernel<<<sb2, 256, 0, stream>>>(hist_all, L2, partials);
    scanB_kernel<<<1, 256, 0, stream>>>(partials, sb2);
    scanC_kernel<<<sb2, 256, 0, stream>>>(hist_all, L2, partials);
    scatter_mm1_kernel<<<nblk1 + mmb, 256, 0, stream>>>(ei, E, nblk1, NB, hist_all,
                                                        rankD, rankS, packD, srcb,
                                                        features, W1f, xb1, n);
    bucket_kernel<<<2 * NB, 256, 0, stream>>>(packD, srcb, hist_all, nblk1, NB, n, E,
                                              row_ptr, col, norm_src, norm_dst);
    aggmm_kernel<1, 0, 8, 1, 0><<<fb, 256, 0, stream>>>(xb1, row_ptr, col, b1,
                                                        norm_dst, norm_src, W2f, xb2, n);
    aggmm_kernel<0, 1, 4, 0, 1><<<fb, 256, 0, stream>>>(xb2, row_ptr, col, b2,
                                                        norm_dst, norm_src, W3f, yb, n);
    agg40_kernel<<<ab, 256, 0, stream>>>(yb, row_ptr, col, norm_dst, b3, (float*)d_out, n);
}